// Round 1
// 327.288 us; speedup vs baseline: 1.0372x; 1.0372x over previous
//
#include <hip/hip_runtime.h>

#define NFEAT 64
#define SCAN_BLOCKS 128

// Counting-sort privatization factors. Block-private histogram rows:
// only ONE workgroup ever touches row b, so workgroup-scope atomics are
// correct by the HIP memory model, and lower to global_atomic_add WITHOUT
// the device-coherence L2-bypass (sc1). v23's device-scope atomics wrote
// through at ~32B/atomic (WRITE_SIZE 78-83MB, 11% HBM, 101+103us).
#define NB_IN  128   // 128 x 200KB rows -> 16 rows/XCD = 3.2MB < 4MB L2
#define NB_OUT 64    // 64 x 400KB rows  ->  8 rows/XCD = 3.2MB < 4MB L2

#define WG_ADD(p, v) \
    __hip_atomic_fetch_add((p), (v), __ATOMIC_RELAXED, __HIP_MEMORY_SCOPE_WORKGROUP)

// ---------------------------------------------------------------------------
// Main path (block-private counting sort, no device-scope atomics anywhere)
// ---------------------------------------------------------------------------

__global__ __launch_bounds__(1024) void v24_hist_in(
        const int* __restrict__ edst, int* __restrict__ cnt_in,
        int E, int n_dst, int Ec) {
    int b = blockIdx.x, t = threadIdx.x, T = blockDim.x;
    int* row = cnt_in + (size_t)b * n_dst;
    // zero private row (int4 stores)
    int n4 = n_dst >> 2;
    int4 z = make_int4(0, 0, 0, 0);
    int4* row4 = (int4*)row;
    for (int i = t; i < n4; i += T) row4[i] = z;
    for (int i = (n4 << 2) + t; i < n_dst; i += T) row[i] = 0;
    __syncthreads();
    int lo = b * Ec;
    int hi = lo + Ec; if (hi > E) hi = E;
    if (lo >= hi) return;
    int cnt = hi - lo;
    int nq = cnt >> 2;   // lo is 16B-aligned (Ec multiple of 4)
    for (int q = t; q < nq; q += T) {
        int i = lo + (q << 2);
        int4 e = *(const int4*)(edst + i);
        if ((unsigned)e.x < (unsigned)n_dst) WG_ADD(&row[e.x], 1);
        if ((unsigned)e.y < (unsigned)n_dst) WG_ADD(&row[e.y], 1);
        if ((unsigned)e.z < (unsigned)n_dst) WG_ADD(&row[e.z], 1);
        if ((unsigned)e.w < (unsigned)n_dst) WG_ADD(&row[e.w], 1);
    }
    for (int i = lo + (nq << 2) + t; i < hi; i += T) {
        int d = edst[i];
        if ((unsigned)d < (unsigned)n_dst) WG_ADD(&row[d], 1);
    }
}

__global__ __launch_bounds__(1024) void v24_hist_out(
        const int* __restrict__ esrc, int* __restrict__ cnt_out,
        int E, int n_src, int Ec) {
    int b = blockIdx.x, t = threadIdx.x, T = blockDim.x;
    int* row = cnt_out + (size_t)b * n_src;
    int n4 = n_src >> 2;
    int4 z = make_int4(0, 0, 0, 0);
    int4* row4 = (int4*)row;
    for (int i = t; i < n4; i += T) row4[i] = z;
    for (int i = (n4 << 2) + t; i < n_src; i += T) row[i] = 0;
    __syncthreads();
    int lo = b * Ec;
    int hi = lo + Ec; if (hi > E) hi = E;
    if (lo >= hi) return;
    int cnt = hi - lo;
    int nq = cnt >> 2;
    for (int q = t; q < nq; q += T) {
        int i = lo + (q << 2);
        int4 e = *(const int4*)(esrc + i);
        if ((unsigned)e.x < (unsigned)n_src) WG_ADD(&row[e.x], 1);
        if ((unsigned)e.y < (unsigned)n_src) WG_ADD(&row[e.y], 1);
        if ((unsigned)e.z < (unsigned)n_src) WG_ADD(&row[e.z], 1);
        if ((unsigned)e.w < (unsigned)n_src) WG_ADD(&row[e.w], 1);
    }
    for (int i = lo + (nq << 2) + t; i < hi; i += T) {
        int s = esrc[i];
        if ((unsigned)s < (unsigned)n_src) WG_ADD(&row[s], 1);
    }
}

// Column sums of both histograms -> deg_in (for scan) + both norm tables.
__global__ void v24_reduce(const int* __restrict__ cnt_in,
                           const int* __restrict__ cnt_out,
                           int* __restrict__ deg_in,
                           float* __restrict__ nsrc, float* __restrict__ ndst,
                           int n_src, int n_dst) {
    int i = blockIdx.x * blockDim.x + threadIdx.x;
    if (i < n_src) {
        const int* p = cnt_out + i;
        int s = 0;
        for (int b = 0; b < NB_OUT; ++b) { s += *p; p += n_src; }
        nsrc[i] = rsqrtf(fmaxf((float)s, 1.0f));
    }
    if (i < n_dst) {
        const int* p = cnt_in + i;
        int s = 0;
        for (int b = 0; b < NB_IN; ++b) { s += *p; p += n_dst; }
        deg_in[i] = s;
        ndst[i] = rsqrtf(fmaxf((float)s, 1.0f));
    }
}

// Turn cnt_in[b][d] in-place into exact write offsets:
// off[b][d] = row_start[d] + sum_{b'<b} cnt[b'][d]
__global__ void v24_coloff(int* __restrict__ cnt_in,
                           const int* __restrict__ row_start, int n_dst) {
    int d = blockIdx.x * blockDim.x + threadIdx.x;
    if (d >= n_dst) return;
    int a = row_start[d];
    int* p = cnt_in + d;
    for (int b = 0; b < NB_IN; ++b) {
        int c = *p;
        *p = a;
        a += c;
        p += n_dst;
    }
}

// Block b re-reads chunk b (same deterministic chunking as hist_in) and
// claims slots with workgroup-scope fetch-add on its private offset row.
__global__ __launch_bounds__(1024) void v24_place(
        const int* __restrict__ esrc, const int* __restrict__ edst,
        int* __restrict__ off, int* __restrict__ sorted_src,
        int E, int n_dst, int Ec) {
    int b = blockIdx.x, t = threadIdx.x, T = blockDim.x;
    int* row = off + (size_t)b * n_dst;
    int lo = b * Ec;
    int hi = lo + Ec; if (hi > E) hi = E;
    if (lo >= hi) return;
    int cnt = hi - lo;
    int nq = cnt >> 2;
    for (int q = t; q < nq; q += T) {
        int i = lo + (q << 2);
        int4 s = *(const int4*)(esrc + i);
        int4 d = *(const int4*)(edst + i);
        if ((unsigned)d.x < (unsigned)n_dst) { int slot = WG_ADD(&row[d.x], 1); sorted_src[slot] = s.x; }
        if ((unsigned)d.y < (unsigned)n_dst) { int slot = WG_ADD(&row[d.y], 1); sorted_src[slot] = s.y; }
        if ((unsigned)d.z < (unsigned)n_dst) { int slot = WG_ADD(&row[d.z], 1); sorted_src[slot] = s.z; }
        if ((unsigned)d.w < (unsigned)n_dst) { int slot = WG_ADD(&row[d.w], 1); sorted_src[slot] = s.w; }
    }
    for (int i = lo + (nq << 2) + t; i < hi; i += T) {
        int s = esrc[i];
        int d = edst[i];
        if ((unsigned)d < (unsigned)n_dst) { int slot = WG_ADD(&row[d], 1); sorted_src[slot] = s; }
    }
}

// Gather, 8x unrolled (was 4x): 8 independent feat-row loads in flight per
// wave; 4x/1x tail ladder. Wave = one dst row, lane = feature.
__global__ void v24_gather(const float* __restrict__ feat,
                           const int* __restrict__ sorted_src,
                           const int* __restrict__ row_start,
                           const float* __restrict__ nsrc,
                           const float* __restrict__ ndst,
                           float* __restrict__ out,
                           int n_src, int n_dst) {
    int gid = blockIdx.x * blockDim.x + threadIdx.x;
    int d = gid >> 6;
    int f = threadIdx.x & 63;
    if (d >= n_dst) return;
    int lo = row_start[d], hi = row_start[d + 1];
    int nmax = n_src - 1;
    float a0 = 0, a1 = 0, a2 = 0, a3 = 0, a4 = 0, a5 = 0, a6 = 0, a7 = 0;
    int k = lo;
    for (; k + 7 < hi; k += 8) {
        int s0 = min(max(sorted_src[k    ], 0), nmax);
        int s1 = min(max(sorted_src[k + 1], 0), nmax);
        int s2 = min(max(sorted_src[k + 2], 0), nmax);
        int s3 = min(max(sorted_src[k + 3], 0), nmax);
        int s4 = min(max(sorted_src[k + 4], 0), nmax);
        int s5 = min(max(sorted_src[k + 5], 0), nmax);
        int s6 = min(max(sorted_src[k + 6], 0), nmax);
        int s7 = min(max(sorted_src[k + 7], 0), nmax);
        float v0 = feat[(size_t)s0 * NFEAT + f];
        float v1 = feat[(size_t)s1 * NFEAT + f];
        float v2 = feat[(size_t)s2 * NFEAT + f];
        float v3 = feat[(size_t)s3 * NFEAT + f];
        float v4 = feat[(size_t)s4 * NFEAT + f];
        float v5 = feat[(size_t)s5 * NFEAT + f];
        float v6 = feat[(size_t)s6 * NFEAT + f];
        float v7 = feat[(size_t)s7 * NFEAT + f];
        a0 += v0 * nsrc[s0];
        a1 += v1 * nsrc[s1];
        a2 += v2 * nsrc[s2];
        a3 += v3 * nsrc[s3];
        a4 += v4 * nsrc[s4];
        a5 += v5 * nsrc[s5];
        a6 += v6 * nsrc[s6];
        a7 += v7 * nsrc[s7];
    }
    for (; k + 3 < hi; k += 4) {
        int s0 = min(max(sorted_src[k    ], 0), nmax);
        int s1 = min(max(sorted_src[k + 1], 0), nmax);
        int s2 = min(max(sorted_src[k + 2], 0), nmax);
        int s3 = min(max(sorted_src[k + 3], 0), nmax);
        a0 += feat[(size_t)s0 * NFEAT + f] * nsrc[s0];
        a1 += feat[(size_t)s1 * NFEAT + f] * nsrc[s1];
        a2 += feat[(size_t)s2 * NFEAT + f] * nsrc[s2];
        a3 += feat[(size_t)s3 * NFEAT + f] * nsrc[s3];
    }
    for (; k < hi; ++k) {
        int s = min(max(sorted_src[k], 0), nmax);
        a0 += feat[(size_t)s * NFEAT + f] * nsrc[s];
    }
    out[d * NFEAT + f] = (((a0 + a1) + (a2 + a3)) + ((a4 + a5) + (a6 + a7))) * ndst[d];
}

// ---------------------------------------------------------------------------
// v23 fallback (proven path) — only used if ws_size can't hold the histograms
// ---------------------------------------------------------------------------

__global__ void v23_zero(int* __restrict__ deg_out, int* __restrict__ deg_in,
                         int n_src, int n_dst) {
    int i = blockIdx.x * blockDim.x + threadIdx.x;
    if (i < n_src) deg_out[i] = 0;
    if (i < n_dst) deg_in[i] = 0;
}

__global__ void v23_deg(const int* __restrict__ esrc, const int* __restrict__ edst,
                        int* __restrict__ deg_out, int* __restrict__ deg_in,
                        int E, int n_src, int n_dst) {
    int i = blockIdx.x * blockDim.x + threadIdx.x;
    if (i >= E) return;
    int s = esrc[i];
    int d = edst[i];
    if ((unsigned)s < (unsigned)n_src) atomicAdd(&deg_out[s], 1);
    if ((unsigned)d < (unsigned)n_dst) atomicAdd(&deg_in[d], 1);
}

__global__ void v23_norm(const int* __restrict__ deg_out, const int* __restrict__ deg_in,
                         float* __restrict__ nsrc, float* __restrict__ ndst,
                         int n_src, int n_dst) {
    int i = blockIdx.x * blockDim.x + threadIdx.x;
    if (i < n_src) nsrc[i] = rsqrtf(fmaxf((float)deg_out[i], 1.0f));
    if (i < n_dst) ndst[i] = rsqrtf(fmaxf((float)deg_in[i], 1.0f));
}

__global__ void v23_scan1(const int* __restrict__ deg_in, int* __restrict__ bsum,
                          int n_dst, int chunk) {
    __shared__ int red[256];
    int b = blockIdx.x, t = threadIdx.x;
    int lo = b * chunk;
    int hi = lo + chunk; if (hi > n_dst) hi = n_dst;
    int s = 0;
    for (int i = lo + t; i < hi; i += 256) s += deg_in[i];
    red[t] = s;
    __syncthreads();
    for (int o = 128; o > 0; o >>= 1) {
        if (t < o) red[t] += red[t + o];
        __syncthreads();
    }
    if (t == 0) bsum[b] = red[0];
}

__global__ void v23_scan2(int* __restrict__ bsum, int* __restrict__ boff,
                          int* __restrict__ row_start, int n_dst) {
    if (threadIdx.x == 0) {
        int a = 0;
        for (int k = 0; k < SCAN_BLOCKS; ++k) { boff[k] = a; a += bsum[k]; }
        row_start[n_dst] = a;
    }
}

__global__ void v23_scan3(const int* __restrict__ deg_in, const int* __restrict__ boff,
                          int* __restrict__ row_start, int* __restrict__ cursor,
                          int n_dst, int chunk) {
    __shared__ int tsum[256];
    int b = blockIdx.x, t = threadIdx.x;
    int lo = b * chunk;
    int hi = lo + chunk; if (hi > n_dst) hi = n_dst;
    int per = (chunk + 255) / 256;
    int mylo = lo + t * per;
    int myhi = mylo + per; if (myhi > hi) myhi = hi;
    int s = 0;
    for (int i = mylo; i < myhi; ++i) s += deg_in[i];
    tsum[t] = s;
    __syncthreads();
    if (t == 0) {
        int a = 0;
        for (int k = 0; k < 256; ++k) { int v = tsum[k]; tsum[k] = a; a += v; }
    }
    __syncthreads();
    int a = boff[b] + tsum[t];
    for (int i = mylo; i < myhi; ++i) {
        row_start[i] = a;
        cursor[i] = a;
        a += deg_in[i];
    }
}

__global__ void v23_place(const int* __restrict__ esrc, const int* __restrict__ edst,
                          int* __restrict__ cursor, int* __restrict__ sorted_src,
                          int E, int n_src, int n_dst) {
    int i = blockIdx.x * blockDim.x + threadIdx.x;
    if (i >= E) return;
    int s = esrc[i];
    int d = edst[i];
    if ((unsigned)s >= (unsigned)n_src) return;
    if ((unsigned)d >= (unsigned)n_dst) return;
    int slot = atomicAdd(&cursor[d], 1);
    sorted_src[slot] = s;
}

// ---------------------------------------------------------------------------

extern "C" void kernel_launch(void* const* d_in, const int* in_sizes, int n_in,
                              void* d_out, int out_size, void* d_ws, size_t ws_size,
                              hipStream_t stream) {
    const float* feat = (const float*)d_in[0];
    const int* esrc = (const int*)d_in[1];
    const int* edst = (const int*)d_in[2];
    float* out = (float*)d_out;

    const int n_src = in_sizes[0] / NFEAT;   // 100000
    const int E     = in_sizes[1];           // 1250000
    const int n_dst = out_size / NFEAT;      // 50000

    const int B = 256;
    int nmax = n_src > n_dst ? n_src : n_dst;
    int chunk = (n_dst + SCAN_BLOCKS - 1) / SCAN_BLOCKS;

    size_t sz_cnt_in  = (size_t)NB_IN  * (size_t)n_dst * 4;
    size_t sz_cnt_out = (size_t)NB_OUT * (size_t)n_src * 4;
    size_t sz_fixed = (size_t)E * 4                 // sorted_src
                    + (size_t)n_dst * 4             // deg_in
                    + (size_t)n_src * 4             // nsrc
                    + (size_t)n_dst * 4             // ndst
                    + (size_t)n_dst * 4             // cursor (scan3 writes it)
                    + (size_t)(n_dst + 1) * 4       // row_start
                    + (size_t)SCAN_BLOCKS * 8 + 256;
    bool big = ws_size >= sz_cnt_in + sz_cnt_out + sz_fixed;

    if (big) {
        char* ws = (char*)d_ws;
        size_t off = 0;
        int*   cnt_in     = (int*)(ws + off);   off += sz_cnt_in;
        int*   cnt_out    = (int*)(ws + off);   off += sz_cnt_out;
        int*   sorted_src = (int*)(ws + off);   off += (size_t)E * 4;
        int*   deg_in     = (int*)(ws + off);   off += (size_t)n_dst * 4;
        float* nsrc       = (float*)(ws + off); off += (size_t)n_src * 4;
        float* ndst       = (float*)(ws + off); off += (size_t)n_dst * 4;
        int*   cursor     = (int*)(ws + off);   off += (size_t)n_dst * 4;
        int*   row_start  = (int*)(ws + off);   off += (size_t)(n_dst + 1) * 4;
        int*   bsum       = (int*)(ws + off);   off += SCAN_BLOCKS * 4;
        int*   boff       = (int*)(ws + off);   off += SCAN_BLOCKS * 4;

        int Ec_in  = (((E + NB_IN  - 1) / NB_IN ) + 3) & ~3;   // 16B-aligned chunks
        int Ec_out = (((E + NB_OUT - 1) / NB_OUT) + 3) & ~3;

        v24_hist_in <<<NB_IN,  1024, 0, stream>>>(edst, cnt_in,  E, n_dst, Ec_in);
        v24_hist_out<<<NB_OUT, 1024, 0, stream>>>(esrc, cnt_out, E, n_src, Ec_out);
        v24_reduce<<<(nmax + B - 1) / B, B, 0, stream>>>(cnt_in, cnt_out, deg_in,
                                                         nsrc, ndst, n_src, n_dst);
        v23_scan1<<<SCAN_BLOCKS, B, 0, stream>>>(deg_in, bsum, n_dst, chunk);
        v23_scan2<<<1, 64, 0, stream>>>(bsum, boff, row_start, n_dst);
        v23_scan3<<<SCAN_BLOCKS, B, 0, stream>>>(deg_in, boff, row_start, cursor,
                                                 n_dst, chunk);
        v24_coloff<<<(n_dst + B - 1) / B, B, 0, stream>>>(cnt_in, row_start, n_dst);
        v24_place<<<NB_IN, 1024, 0, stream>>>(esrc, edst, cnt_in, sorted_src,
                                              E, n_dst, Ec_in);
        long long gthreads = (long long)n_dst * 64;
        v24_gather<<<(int)((gthreads + B - 1) / B), B, 0, stream>>>(feat, sorted_src,
                                                                    row_start, nsrc, ndst,
                                                                    out, n_src, n_dst);
    } else {
        // v23 fallback layout
        char* ws = (char*)d_ws;
        size_t off = 0;
        int*   deg_out    = (int*)(ws + off);   off += (size_t)n_src * 4;
        int*   deg_in     = (int*)(ws + off);   off += (size_t)n_dst * 4;
        float* nsrc       = (float*)(ws + off); off += (size_t)n_src * 4;
        float* ndst       = (float*)(ws + off); off += (size_t)n_dst * 4;
        int*   row_start  = (int*)(ws + off);   off += (size_t)(n_dst + 1) * 4;
        int*   cursor     = (int*)(ws + off);   off += (size_t)n_dst * 4;
        int*   bsum       = (int*)(ws + off);   off += SCAN_BLOCKS * 4;
        int*   boff       = (int*)(ws + off);   off += SCAN_BLOCKS * 4;
        int*   sorted_src = (int*)(ws + off);   off += (size_t)E * 4;

        v23_zero<<<(nmax + B - 1) / B, B, 0, stream>>>(deg_out, deg_in, n_src, n_dst);
        v23_deg<<<(E + B - 1) / B, B, 0, stream>>>(esrc, edst, deg_out, deg_in,
                                                   E, n_src, n_dst);
        v23_norm<<<(nmax + B - 1) / B, B, 0, stream>>>(deg_out, deg_in, nsrc, ndst,
                                                       n_src, n_dst);
        v23_scan1<<<SCAN_BLOCKS, B, 0, stream>>>(deg_in, bsum, n_dst, chunk);
        v23_scan2<<<1, 64, 0, stream>>>(bsum, boff, row_start, n_dst);
        v23_scan3<<<SCAN_BLOCKS, B, 0, stream>>>(deg_in, boff, row_start, cursor,
                                                 n_dst, chunk);
        v23_place<<<(E + B - 1) / B, B, 0, stream>>>(esrc, edst, cursor, sorted_src,
                                                     E, n_src, n_dst);
        long long gthreads = (long long)n_dst * 64;
        v24_gather<<<(int)((gthreads + B - 1) / B), B, 0, stream>>>(feat, sorted_src,
                                                                    row_start, nsrc, ndst,
                                                                    out, n_src, n_dst);
    }
}

// Round 2
// 191.906 us; speedup vs baseline: 1.7689x; 1.7055x over previous
//
#include <hip/hip_runtime.h>

#define NFEAT 64
#define SCAN_BLOCKS 128

// v25: all histogram/rank atomics moved to LDS (ds_add_u32 — zero fabric
// traffic). R1 post-mortem: workgroup-scope GLOBAL atomics still write
// ~32B/op to the fabric (hist_out WRITE_SIZE 62.5MB = 25.6 zero + 40MB
// atomics) AND 64 blocks left occupancy at 7.7%. LDS histograms over
// 12.8K-wide id ranges fix both: no global atomics, 512-block grids.
#define RANGE 12800          // LDS int histogram: 51200 B (< 64KB static)
#define NB_IN 128            // edge chunks for dst-side (rows of cnt_in)
#define NB_OUT 64            // edge chunks for src-side (rows of cnt_out)

// ---------------------------------------------------------------------------
// Main path
// ---------------------------------------------------------------------------

// Block (b,y): LDS-histogram chunk b of idx[] over id range [y*RANGE, ...),
// flush as ushort row slice (plain stores, coalesced). Counts fit ushort:
// count <= chunk size (~19.5K) < 65536.
__global__ __launch_bounds__(1024) void v25_hist(
        const int* __restrict__ idx, unsigned short* __restrict__ cnt,
        int E, int n, int Ec) {
    __shared__ int lh[RANGE];
    int b = blockIdx.x, y = blockIdx.y, t = threadIdx.x, T = blockDim.x;
    int rbase = y * RANGE;
    int rend = rbase + RANGE; if (rend > n) rend = n;
    int W = rend - rbase;
    if (W <= 0) return;
    for (int i = t; i < W; i += T) lh[i] = 0;
    __syncthreads();
    int lo = b * Ec;
    int hi = lo + Ec; if (hi > E) hi = E;
    if (lo < hi) {
        int cntE = hi - lo;
        int nq = cntE >> 2;                 // lo is 16B-aligned (Ec % 4 == 0)
        for (int q = t; q < nq; q += T) {
            int i = lo + (q << 2);
            int4 e = *(const int4*)(idx + i);
            unsigned rx = (unsigned)(e.x - rbase); if (rx < (unsigned)W) atomicAdd(&lh[rx], 1);
            unsigned ry = (unsigned)(e.y - rbase); if (ry < (unsigned)W) atomicAdd(&lh[ry], 1);
            unsigned rz = (unsigned)(e.z - rbase); if (rz < (unsigned)W) atomicAdd(&lh[rz], 1);
            unsigned rw = (unsigned)(e.w - rbase); if (rw < (unsigned)W) atomicAdd(&lh[rw], 1);
        }
        for (int i = lo + (nq << 2) + t; i < hi; i += T) {
            unsigned r = (unsigned)(idx[i] - rbase);
            if (r < (unsigned)W) atomicAdd(&lh[r], 1);
        }
    }
    __syncthreads();
    unsigned short* row = cnt + (size_t)b * n + rbase;
    for (int i = t; i < W; i += T) row[i] = (unsigned short)lh[i];
}

// nsrc from column sums of cnt_out.
__global__ void v25_nsrc(const unsigned short* __restrict__ cnt_out,
                         float* __restrict__ nsrc, int n_src) {
    int i = blockIdx.x * blockDim.x + threadIdx.x;
    if (i >= n_src) return;
    const unsigned short* p = cnt_out + i;
    int s = 0;
    for (int b = 0; b < NB_OUT; ++b) { s += *p; p += n_src; }
    nsrc[i] = rsqrtf(fmaxf((float)s, 1.0f));
}

// Column-wise exclusive prefix over b, IN PLACE: cnt_in[b][d] -> pre[b][d]
// (= #edges with dst d in chunks < b; fits ushort since deg(d) << 65536
// for this graph). Total -> deg_in + ndst in the same pass.
__global__ void v25_prein(unsigned short* __restrict__ cnt_in,
                          int* __restrict__ deg_in, float* __restrict__ ndst,
                          int n_dst) {
    int d = blockIdx.x * blockDim.x + threadIdx.x;
    if (d >= n_dst) return;
    unsigned short* p = cnt_in + d;
    int a = 0;
    for (int b = 0; b < NB_IN; ++b) {
        int c = *p;
        *p = (unsigned short)a;
        a += c;
        p += n_dst;
    }
    deg_in[d] = a;
    ndst[d] = rsqrtf(fmaxf((float)a, 1.0f));
}

// Block (b,y): re-read chunk b; rank via LDS atomicAdd (rtn);
// slot = row_start[d] + pre[b][d] + rank. No global atomics.
__global__ __launch_bounds__(1024) void v25_place(
        const int* __restrict__ esrc, const int* __restrict__ edst,
        const unsigned short* __restrict__ pre, const int* __restrict__ row_start,
        int* __restrict__ sorted_src, int E, int n_dst, int Ec) {
    __shared__ int lh[RANGE];
    int b = blockIdx.x, y = blockIdx.y, t = threadIdx.x, T = blockDim.x;
    int rbase = y * RANGE;
    int rend = rbase + RANGE; if (rend > n_dst) rend = n_dst;
    int W = rend - rbase;
    if (W <= 0) return;
    for (int i = t; i < W; i += T) lh[i] = 0;
    __syncthreads();
    int lo = b * Ec;
    int hi = lo + Ec; if (hi > E) hi = E;
    if (lo >= hi) return;
    const unsigned short* prow = pre + (size_t)b * n_dst;
    int cntE = hi - lo;
    int nq = cntE >> 2;
#define V25_PL(dd, ss)                                                        \
    {                                                                         \
        unsigned r = (unsigned)((dd) - rbase);                                \
        if (r < (unsigned)W) {                                                \
            int rank = atomicAdd(&lh[r], 1);                                  \
            int slot = row_start[dd] + (int)prow[dd] + rank;                  \
            if ((unsigned)slot < (unsigned)E) sorted_src[slot] = (ss);        \
        }                                                                     \
    }
    for (int q = t; q < nq; q += T) {
        int i = lo + (q << 2);
        int4 dv = *(const int4*)(edst + i);
        int4 sv = *(const int4*)(esrc + i);
        V25_PL(dv.x, sv.x)
        V25_PL(dv.y, sv.y)
        V25_PL(dv.z, sv.z)
        V25_PL(dv.w, sv.w)
    }
    for (int i = lo + (nq << 2) + t; i < hi; i += T) {
        int d = edst[i];
        int s = esrc[i];
        V25_PL(d, s)
    }
#undef V25_PL
}

// Gather, 8x unrolled: 8 independent feat-row loads in flight per wave;
// 4x/1x tail ladder. Wave = one dst row, lane = feature.
__global__ void v24_gather(const float* __restrict__ feat,
                           const int* __restrict__ sorted_src,
                           const int* __restrict__ row_start,
                           const float* __restrict__ nsrc,
                           const float* __restrict__ ndst,
                           float* __restrict__ out,
                           int n_src, int n_dst) {
    int gid = blockIdx.x * blockDim.x + threadIdx.x;
    int d = gid >> 6;
    int f = threadIdx.x & 63;
    if (d >= n_dst) return;
    int lo = row_start[d], hi = row_start[d + 1];
    int nmax = n_src - 1;
    float a0 = 0, a1 = 0, a2 = 0, a3 = 0, a4 = 0, a5 = 0, a6 = 0, a7 = 0;
    int k = lo;
    for (; k + 7 < hi; k += 8) {
        int s0 = min(max(sorted_src[k    ], 0), nmax);
        int s1 = min(max(sorted_src[k + 1], 0), nmax);
        int s2 = min(max(sorted_src[k + 2], 0), nmax);
        int s3 = min(max(sorted_src[k + 3], 0), nmax);
        int s4 = min(max(sorted_src[k + 4], 0), nmax);
        int s5 = min(max(sorted_src[k + 5], 0), nmax);
        int s6 = min(max(sorted_src[k + 6], 0), nmax);
        int s7 = min(max(sorted_src[k + 7], 0), nmax);
        float v0 = feat[(size_t)s0 * NFEAT + f];
        float v1 = feat[(size_t)s1 * NFEAT + f];
        float v2 = feat[(size_t)s2 * NFEAT + f];
        float v3 = feat[(size_t)s3 * NFEAT + f];
        float v4 = feat[(size_t)s4 * NFEAT + f];
        float v5 = feat[(size_t)s5 * NFEAT + f];
        float v6 = feat[(size_t)s6 * NFEAT + f];
        float v7 = feat[(size_t)s7 * NFEAT + f];
        a0 += v0 * nsrc[s0];
        a1 += v1 * nsrc[s1];
        a2 += v2 * nsrc[s2];
        a3 += v3 * nsrc[s3];
        a4 += v4 * nsrc[s4];
        a5 += v5 * nsrc[s5];
        a6 += v6 * nsrc[s6];
        a7 += v7 * nsrc[s7];
    }
    for (; k + 3 < hi; k += 4) {
        int s0 = min(max(sorted_src[k    ], 0), nmax);
        int s1 = min(max(sorted_src[k + 1], 0), nmax);
        int s2 = min(max(sorted_src[k + 2], 0), nmax);
        int s3 = min(max(sorted_src[k + 3], 0), nmax);
        a0 += feat[(size_t)s0 * NFEAT + f] * nsrc[s0];
        a1 += feat[(size_t)s1 * NFEAT + f] * nsrc[s1];
        a2 += feat[(size_t)s2 * NFEAT + f] * nsrc[s2];
        a3 += feat[(size_t)s3 * NFEAT + f] * nsrc[s3];
    }
    for (; k < hi; ++k) {
        int s = min(max(sorted_src[k], 0), nmax);
        a0 += feat[(size_t)s * NFEAT + f] * nsrc[s];
    }
    out[d * NFEAT + f] = (((a0 + a1) + (a2 + a3)) + ((a4 + a5) + (a6 + a7))) * ndst[d];
}

// ---------------------------------------------------------------------------
// Scan (row_start from deg_in) — unchanged, proven
// ---------------------------------------------------------------------------

__global__ void v23_scan1(const int* __restrict__ deg_in, int* __restrict__ bsum,
                          int n_dst, int chunk) {
    __shared__ int red[256];
    int b = blockIdx.x, t = threadIdx.x;
    int lo = b * chunk;
    int hi = lo + chunk; if (hi > n_dst) hi = n_dst;
    int s = 0;
    for (int i = lo + t; i < hi; i += 256) s += deg_in[i];
    red[t] = s;
    __syncthreads();
    for (int o = 128; o > 0; o >>= 1) {
        if (t < o) red[t] += red[t + o];
        __syncthreads();
    }
    if (t == 0) bsum[b] = red[0];
}

__global__ void v23_scan2(int* __restrict__ bsum, int* __restrict__ boff,
                          int* __restrict__ row_start, int n_dst) {
    if (threadIdx.x == 0) {
        int a = 0;
        for (int k = 0; k < SCAN_BLOCKS; ++k) { boff[k] = a; a += bsum[k]; }
        row_start[n_dst] = a;
    }
}

__global__ void v23_scan3(const int* __restrict__ deg_in, const int* __restrict__ boff,
                          int* __restrict__ row_start, int* __restrict__ cursor,
                          int n_dst, int chunk) {
    __shared__ int tsum[256];
    int b = blockIdx.x, t = threadIdx.x;
    int lo = b * chunk;
    int hi = lo + chunk; if (hi > n_dst) hi = n_dst;
    int per = (chunk + 255) / 256;
    int mylo = lo + t * per;
    int myhi = mylo + per; if (myhi > hi) myhi = hi;
    int s = 0;
    for (int i = mylo; i < myhi; ++i) s += deg_in[i];
    tsum[t] = s;
    __syncthreads();
    if (t == 0) {
        int a = 0;
        for (int k = 0; k < 256; ++k) { int v = tsum[k]; tsum[k] = a; a += v; }
    }
    __syncthreads();
    int a = boff[b] + tsum[t];
    for (int i = mylo; i < myhi; ++i) {
        row_start[i] = a;
        cursor[i] = a;
        a += deg_in[i];
    }
}

// ---------------------------------------------------------------------------
// v23 fallback (proven path) — only if ws_size can't hold the histograms
// ---------------------------------------------------------------------------

__global__ void v23_zero(int* __restrict__ deg_out, int* __restrict__ deg_in,
                         int n_src, int n_dst) {
    int i = blockIdx.x * blockDim.x + threadIdx.x;
    if (i < n_src) deg_out[i] = 0;
    if (i < n_dst) deg_in[i] = 0;
}

__global__ void v23_deg(const int* __restrict__ esrc, const int* __restrict__ edst,
                        int* __restrict__ deg_out, int* __restrict__ deg_in,
                        int E, int n_src, int n_dst) {
    int i = blockIdx.x * blockDim.x + threadIdx.x;
    if (i >= E) return;
    int s = esrc[i];
    int d = edst[i];
    if ((unsigned)s < (unsigned)n_src) atomicAdd(&deg_out[s], 1);
    if ((unsigned)d < (unsigned)n_dst) atomicAdd(&deg_in[d], 1);
}

__global__ void v23_norm(const int* __restrict__ deg_out, const int* __restrict__ deg_in,
                         float* __restrict__ nsrc, float* __restrict__ ndst,
                         int n_src, int n_dst) {
    int i = blockIdx.x * blockDim.x + threadIdx.x;
    if (i < n_src) nsrc[i] = rsqrtf(fmaxf((float)deg_out[i], 1.0f));
    if (i < n_dst) ndst[i] = rsqrtf(fmaxf((float)deg_in[i], 1.0f));
}

__global__ void v23_place(const int* __restrict__ esrc, const int* __restrict__ edst,
                          int* __restrict__ cursor, int* __restrict__ sorted_src,
                          int E, int n_src, int n_dst) {
    int i = blockIdx.x * blockDim.x + threadIdx.x;
    if (i >= E) return;
    int s = esrc[i];
    int d = edst[i];
    if ((unsigned)s >= (unsigned)n_src) return;
    if ((unsigned)d >= (unsigned)n_dst) return;
    int slot = atomicAdd(&cursor[d], 1);
    sorted_src[slot] = s;
}

// ---------------------------------------------------------------------------

extern "C" void kernel_launch(void* const* d_in, const int* in_sizes, int n_in,
                              void* d_out, int out_size, void* d_ws, size_t ws_size,
                              hipStream_t stream) {
    const float* feat = (const float*)d_in[0];
    const int* esrc = (const int*)d_in[1];
    const int* edst = (const int*)d_in[2];
    float* out = (float*)d_out;

    const int n_src = in_sizes[0] / NFEAT;   // 100000
    const int E     = in_sizes[1];           // 1250000
    const int n_dst = out_size / NFEAT;      // 50000

    const int B = 256;
    int nmax = n_src > n_dst ? n_src : n_dst;
    int chunk = (n_dst + SCAN_BLOCKS - 1) / SCAN_BLOCKS;

    size_t sz_cnt_in  = ((size_t)NB_IN  * (size_t)n_dst * 2 + 255) & ~(size_t)255;
    size_t sz_cnt_out = ((size_t)NB_OUT * (size_t)n_src * 2 + 255) & ~(size_t)255;
    size_t sz_fixed = (size_t)E * 4                 // sorted_src
                    + (size_t)n_dst * 4             // deg_in
                    + (size_t)n_src * 4             // nsrc
                    + (size_t)n_dst * 4             // ndst
                    + (size_t)n_dst * 4             // cursor
                    + (size_t)(n_dst + 1) * 4       // row_start
                    + (size_t)SCAN_BLOCKS * 8 + 512;
    bool big = ws_size >= sz_cnt_in + sz_cnt_out + sz_fixed;

    if (big) {
        char* ws = (char*)d_ws;
        size_t off = 0;
        unsigned short* cnt_in  = (unsigned short*)(ws + off); off += sz_cnt_in;
        unsigned short* cnt_out = (unsigned short*)(ws + off); off += sz_cnt_out;
        int*   sorted_src = (int*)(ws + off);   off += (size_t)E * 4;
        int*   deg_in     = (int*)(ws + off);   off += (size_t)n_dst * 4;
        float* nsrc       = (float*)(ws + off); off += (size_t)n_src * 4;
        float* ndst       = (float*)(ws + off); off += (size_t)n_dst * 4;
        int*   cursor     = (int*)(ws + off);   off += (size_t)n_dst * 4;
        int*   row_start  = (int*)(ws + off);   off += (size_t)(n_dst + 1) * 4;
        int*   bsum       = (int*)(ws + off);   off += SCAN_BLOCKS * 4;
        int*   boff       = (int*)(ws + off);   off += SCAN_BLOCKS * 4;

        int Ec_in  = (((E + NB_IN  - 1) / NB_IN ) + 3) & ~3;   // 16B-aligned chunks
        int Ec_out = (((E + NB_OUT - 1) / NB_OUT) + 3) & ~3;
        int P_in  = (n_dst + RANGE - 1) / RANGE;               // 4
        int P_out = (n_src + RANGE - 1) / RANGE;               // 8

        dim3 gout(NB_OUT, P_out), gin(NB_IN, P_in);

        v25_hist<<<gout, 1024, 0, stream>>>(esrc, cnt_out, E, n_src, Ec_out);
        v25_hist<<<gin,  1024, 0, stream>>>(edst, cnt_in,  E, n_dst, Ec_in);
        v25_nsrc<<<(n_src + B - 1) / B, B, 0, stream>>>(cnt_out, nsrc, n_src);
        v25_prein<<<(n_dst + B - 1) / B, B, 0, stream>>>(cnt_in, deg_in, ndst, n_dst);
        v23_scan1<<<SCAN_BLOCKS, B, 0, stream>>>(deg_in, bsum, n_dst, chunk);
        v23_scan2<<<1, 64, 0, stream>>>(bsum, boff, row_start, n_dst);
        v23_scan3<<<SCAN_BLOCKS, B, 0, stream>>>(deg_in, boff, row_start, cursor,
                                                 n_dst, chunk);
        v25_place<<<gin, 1024, 0, stream>>>(esrc, edst, cnt_in, row_start,
                                            sorted_src, E, n_dst, Ec_in);
        long long gthreads = (long long)n_dst * 64;
        v24_gather<<<(int)((gthreads + B - 1) / B), B, 0, stream>>>(feat, sorted_src,
                                                                    row_start, nsrc, ndst,
                                                                    out, n_src, n_dst);
    } else {
        // v23 fallback layout
        char* ws = (char*)d_ws;
        size_t off = 0;
        int*   deg_out    = (int*)(ws + off);   off += (size_t)n_src * 4;
        int*   deg_in     = (int*)(ws + off);   off += (size_t)n_dst * 4;
        float* nsrc       = (float*)(ws + off); off += (size_t)n_src * 4;
        float* ndst       = (float*)(ws + off); off += (size_t)n_dst * 4;
        int*   row_start  = (int*)(ws + off);   off += (size_t)(n_dst + 1) * 4;
        int*   cursor     = (int*)(ws + off);   off += (size_t)n_dst * 4;
        int*   bsum       = (int*)(ws + off);   off += SCAN_BLOCKS * 4;
        int*   boff       = (int*)(ws + off);   off += SCAN_BLOCKS * 4;
        int*   sorted_src = (int*)(ws + off);   off += (size_t)E * 4;

        v23_zero<<<(nmax + B - 1) / B, B, 0, stream>>>(deg_out, deg_in, n_src, n_dst);
        v23_deg<<<(E + B - 1) / B, B, 0, stream>>>(esrc, edst, deg_out, deg_in,
                                                   E, n_src, n_dst);
        v23_norm<<<(nmax + B - 1) / B, B, 0, stream>>>(deg_out, deg_in, nsrc, ndst,
                                                       n_src, n_dst);
        v23_scan1<<<SCAN_BLOCKS, B, 0, stream>>>(deg_in, bsum, n_dst, chunk);
        v23_scan2<<<1, 64, 0, stream>>>(bsum, boff, row_start, n_dst);
        v23_scan3<<<SCAN_BLOCKS, B, 0, stream>>>(deg_in, boff, row_start, cursor,
                                                 n_dst, chunk);
        v23_place<<<(E + B - 1) / B, B, 0, stream>>>(esrc, edst, cursor, sorted_src,
                                                     E, n_src, n_dst);
        long long gthreads = (long long)n_dst * 64;
        v24_gather<<<(int)((gthreads + B - 1) / B), B, 0, stream>>>(feat, sorted_src,
                                                                    row_start, nsrc, ndst,
                                                                    out, n_src, n_dst);
    }
}